// Round 8
// baseline (56.600 us; speedup 1.0000x reference)
//
#include <hip/hip_runtime.h>
#include <hip/hip_cooperative_groups.h>
#include <math.h>

namespace cg = cooperative_groups;

#define B_SZ 2
#define T_SZ 512
#define D_SZ 64
#define ELEMS 4096            // D*D

// ws layout: decay_t [B][D][T] at 0 (256 KB); M=mu*rs [B*T]; R=rs [B*T]
#define DECAY_BYTES ((size_t)B_SZ * D_SZ * T_SZ * 4)
#define M_OFF   DECAY_BYTES
#define R_OFF   (DECAY_BYTES + (size_t)B_SZ * T_SZ * 4)

// ---------------- single cooperative kernel ----------------
// grid 256 x 512. Phase 1: 4 (b,t)-slices per block (stats+decay).
// grid.sync. Phase 2: block=(b,r,col-half), 16 chunks x 32 cols, CLEN=32,
// two-sweep local scan + LDS carry fold.
__global__ __launch_bounds__(512, 2) void fused_ssm_kernel(
    const float* __restrict__ x, const float* __restrict__ log_A,
    const float* __restrict__ dt_w, const float* __restrict__ dt_b,
    const float* __restrict__ ln_w, const float* __restrict__ ln_b,
    float* __restrict__ decay_t, float* __restrict__ Mst, float* __restrict__ Rst,
    float* __restrict__ out)
{
    const int tid = threadIdx.x;
    __shared__ float sred[16];

    // ---- Phase 1 ----
    {
        const int lane = tid & 63;
        const int wv   = tid >> 6;
        // hoisted per-thread constants: this thread's 8 elements
        const int ebase = tid * 8;           // element index within a slice
        const int r1    = ebase >> 6;        // row (same for all 8)
        const float4 w4a = *reinterpret_cast<const float4*>(ln_w + ebase);
        const float4 w4b = *reinterpret_cast<const float4*>(ln_w + ebase + 4);
        const float4 b4a = *reinterpret_cast<const float4*>(ln_b + ebase);
        const float4 b4b = *reinterpret_cast<const float4*>(ln_b + ebase + 4);
        const int cbase = ebase & 63;        // column of first elem
        const float4 dwa = *reinterpret_cast<const float4*>(dt_w + cbase);
        const float4 dwb = *reinterpret_cast<const float4*>(dt_w + cbase + 4);
        const float db   = dt_b[0];
        const float Arow = -expf(log_A[r1]); // only used by group leader

        for (int s = 0; s < 4; ++s) {
            const int bt = blockIdx.x * 4 + s;
            const size_t base = (size_t)bt * ELEMS + ebase;
            const float4 xa = *reinterpret_cast<const float4*>(x + base);
            const float4 xb = *reinterpret_cast<const float4*>(x + base + 4);

            float sum = xa.x + xa.y + xa.z + xa.w + xb.x + xb.y + xb.z + xb.w;
            float ssq = xa.x*xa.x + xa.y*xa.y + xa.z*xa.z + xa.w*xa.w
                      + xb.x*xb.x + xb.y*xb.y + xb.z*xb.z + xb.w*xb.w;
#pragma unroll
            for (int off = 32; off; off >>= 1) {
                sum += __shfl_down(sum, off);
                ssq += __shfl_down(ssq, off);
            }
            if (lane == 0) { sred[wv] = sum; sred[8 + wv] = ssq; }
            __syncthreads();
            sum = sred[0]+sred[1]+sred[2]+sred[3]+sred[4]+sred[5]+sred[6]+sred[7];
            ssq = sred[8]+sred[9]+sred[10]+sred[11]+sred[12]+sred[13]+sred[14]+sred[15];
            __syncthreads();   // allow sred reuse next slice

            const float mu = sum * (1.f / ELEMS);
            const float var = ssq * (1.f / ELEMS) - mu * mu;
            const float rs = rsqrtf(var + 1e-5f);

            // dot of normalized row with dt_w over this thread's 8 elems
            float dp;
            {
                float xn0 = fmaf((xa.x - mu) * rs, w4a.x, b4a.x);
                float xn1 = fmaf((xa.y - mu) * rs, w4a.y, b4a.y);
                float xn2 = fmaf((xa.z - mu) * rs, w4a.z, b4a.z);
                float xn3 = fmaf((xa.w - mu) * rs, w4a.w, b4a.w);
                float xn4 = fmaf((xb.x - mu) * rs, w4b.x, b4b.x);
                float xn5 = fmaf((xb.y - mu) * rs, w4b.y, b4b.y);
                float xn6 = fmaf((xb.z - mu) * rs, w4b.z, b4b.z);
                float xn7 = fmaf((xb.w - mu) * rs, w4b.w, b4b.w);
                dp = xn0*dwa.x + xn1*dwa.y + xn2*dwa.z + xn3*dwa.w
                   + xn4*dwb.x + xn5*dwb.y + xn6*dwb.z + xn7*dwb.w;
            }
            // reduce over the 8 lanes sharing this row (aligned 8-groups)
            dp += __shfl_xor(dp, 1);
            dp += __shfl_xor(dp, 2);
            dp += __shfl_xor(dp, 4);

            if ((tid & 7) == 0) {
                const int b = bt >> 9;
                const int t = bt & (T_SZ - 1);
                const float z = dp + db;
                const float dt = (z > 20.f) ? z : log1pf(expf(z));
                decay_t[((size_t)(b * D_SZ + r1)) * T_SZ + t] = expf(dt * Arow);
            }
            if (tid == 0) { Mst[bt] = mu * rs; Rst[bt] = rs; }
        }
    }

    cg::this_grid().sync();

    // ---- Phase 2 ----
    {
        const int col = tid & 31;             // 0..31
        const int k   = tid >> 5;             // chunk 0..15
        const int ch  = blockIdx.x & 1;       // col-half
        const int r   = (blockIdx.x >> 1) & 63;
        const int b   = blockIdx.x >> 7;
        const int c   = ch * 32 + col;
        const int t0  = k * 32;               // CLEN = 32

        __shared__ float sd[T_SZ];
        __shared__ float sM[T_SZ];
        __shared__ float sR[T_SZ];
        __shared__ float sS[16][32];
        __shared__ float sP[16];

        if (tid < T_SZ) {
            sd[tid] = decay_t[((size_t)(b * D_SZ + r)) * T_SZ + tid];
            sM[tid] = Mst[b * T_SZ + tid];
            sR[tid] = Rst[b * T_SZ + tid];
        }
        const float wl = ln_w[r * D_SZ + c];
        const float bl = ln_b[r * D_SZ + c];
        __syncthreads();

        const float* xp = x + ((size_t)(b * T_SZ + t0) * D_SZ + r) * D_SZ + c;

        // sweep 1: tail only
        float S = 0.f;
#pragma unroll
        for (int i = 0; i < 32; ++i) {
            const float xv = xp[(size_t)i * ELEMS];
            const int   t  = t0 + i;
            const float xn = fmaf(fmaf(xv, sR[t], -sM[t]), wl, bl);
            S = fmaf(S, sd[t], xn);
        }
        float P = 1.f;
#pragma unroll
        for (int i = 0; i < 32; ++i) P *= sd[t0 + i];

        sS[k][col] = S;
        if (col == 0) sP[k] = P;
        __syncthreads();

        float Cin = 0.f;
        for (int j = 0; j < k; ++j)
            Cin = fmaf(sP[j], Cin, sS[j][col]);

        // sweep 2: recompute local scan (x L1/L2-hot), apply, write
        float* op = out + ((size_t)(b * T_SZ + t0) * D_SZ + r) * D_SZ + c;
        float S2 = 0.f, cp = 1.f;
#pragma unroll
        for (int i = 0; i < 32; ++i) {
            const float xv = xp[(size_t)i * ELEMS];
            const int   t  = t0 + i;
            const float xn = fmaf(fmaf(xv, sR[t], -sM[t]), wl, bl);
            S2 = fmaf(S2, sd[t], xn);
            cp *= sd[t];
            op[(size_t)i * ELEMS] = fmaf(cp, Cin, S2);
        }
    }
}

// ---------------- fallback path (round-6, two kernels) ----------------
#define NCH  32
#define CLEN 16
#define NCOL 16

__global__ __launch_bounds__(256) void ln_dt_kernel(
    const float* __restrict__ x, const float* __restrict__ log_A,
    const float* __restrict__ dt_w, const float* __restrict__ dt_b,
    const float* __restrict__ ln_w, const float* __restrict__ ln_b,
    float* __restrict__ decay_t, float* __restrict__ Mst, float* __restrict__ Rst)
{
    const int bt  = blockIdx.x;
    const int tid = threadIdx.x;
    const size_t base = (size_t)bt * ELEMS;

    float4 v[4];
    float sum = 0.f, sumsq = 0.f;
    const float4* xv4 = reinterpret_cast<const float4*>(x + base);
#pragma unroll
    for (int k = 0; k < 4; ++k) {
        v[k] = xv4[tid + 256 * k];
        sum   += v[k].x + v[k].y + v[k].z + v[k].w;
        sumsq += v[k].x * v[k].x + v[k].y * v[k].y + v[k].z * v[k].z + v[k].w * v[k].w;
    }

    __shared__ float red0[4], red1[4];
#pragma unroll
    for (int off = 32; off; off >>= 1) {
        sum   += __shfl_down(sum, off);
        sumsq += __shfl_down(sumsq, off);
    }
    const int wave = tid >> 6;
    if ((tid & 63) == 0) { red0[wave] = sum; red1[wave] = sumsq; }
    __syncthreads();
    sum   = red0[0] + red0[1] + red0[2] + red0[3];
    sumsq = red1[0] + red1[1] + red1[2] + red1[3];

    const float mu = sum * (1.f / ELEMS);
    const float var = sumsq * (1.f / ELEMS) - mu * mu;
    const float rs = rsqrtf(var + 1e-5f);

    const float4* w4p = reinterpret_cast<const float4*>(ln_w);
    const float4* b4p = reinterpret_cast<const float4*>(ln_b);
    const float4* dw4 = reinterpret_cast<const float4*>(dt_w);
    float dot[4] = {0.f, 0.f, 0.f, 0.f};
#pragma unroll
    for (int k = 0; k < 4; ++k) {
        const int f = tid + 256 * k;
        float4 w4 = w4p[f];
        float4 b4 = b4p[f];
        float4 xn;
        xn.x = (v[k].x - mu) * rs * w4.x + b4.x;
        xn.y = (v[k].y - mu) * rs * w4.y + b4.y;
        xn.z = (v[k].z - mu) * rs * w4.z + b4.z;
        xn.w = (v[k].w - mu) * rs * w4.w + b4.w;
        float4 wv = dw4[f & 15];
        dot[k] += xn.x * wv.x + xn.y * wv.y + xn.z * wv.z + xn.w * wv.w;
    }

#pragma unroll
    for (int m = 1; m <= 8; m <<= 1) {
#pragma unroll
        for (int k = 0; k < 4; ++k) dot[k] += __shfl_xor(dot[k], m);
    }

    if (tid == 0) { Mst[bt] = mu * rs; Rst[bt] = rs; }

    if ((tid & 15) == 0) {
        const int m = tid >> 4;
        const float db = dt_b[0];
        const int b = bt >> 9;
        const int t = bt & (T_SZ - 1);
#pragma unroll
        for (int k = 0; k < 4; ++k) {
            const int r = m + 16 * k;
            const float z = dot[k] + db;
            const float dt = (z > 20.f) ? z : log1pf(expf(z));
            const float A = -expf(log_A[r]);
            decay_t[((size_t)(b * D_SZ + r)) * T_SZ + t] = expf(dt * A);
        }
    }
}

__global__ __launch_bounds__(512, 4) void scan_fused_kernel(
    const float* __restrict__ x,
    const float* __restrict__ Mst, const float* __restrict__ Rst,
    const float* __restrict__ decay_t,
    const float* __restrict__ ln_w, const float* __restrict__ ln_b,
    float* __restrict__ out)
{
    const int tid = threadIdx.x;
    const int col = tid & (NCOL - 1);
    const int k   = tid >> 4;
    const int row = blockIdx.x >> 2;
    const int cq  = blockIdx.x & 3;
    const int b = row >> 6;
    const int r = row & 63;
    const int c = cq * NCOL + col;
    const int t0 = k * CLEN;

    float4 dv[4], Mv[4], Rv[4];
    const float4* dp = reinterpret_cast<const float4*>(decay_t + (size_t)row * T_SZ + t0);
    const float4* Mp = reinterpret_cast<const float4*>(Mst + b * T_SZ + t0);
    const float4* Rp = reinterpret_cast<const float4*>(Rst + b * T_SZ + t0);
#pragma unroll
    for (int q = 0; q < 4; ++q) { dv[q] = dp[q]; Mv[q] = Mp[q]; Rv[q] = Rp[q]; }
    const float* df = reinterpret_cast<const float*>(dv);
    const float* Mf = reinterpret_cast<const float*>(Mv);
    const float* Rf = reinterpret_cast<const float*>(Rv);

    const float wr = ln_w[r * D_SZ + c];
    const float br = ln_b[r * D_SZ + c];
    const float* xp = x + ((size_t)(b * T_SZ + t0) * D_SZ + r) * D_SZ + c;

    float v[CLEN];
    float S = 0.f;
#pragma unroll
    for (int i = 0; i < CLEN; ++i) {
        const float xv = xp[(size_t)i * ELEMS];
        const float xn = fmaf(fmaf(xv, Rf[i], -Mf[i]), wr, br);
        S = fmaf(S, df[i], xn);
        v[i] = S;
    }

    float P = 1.f;
#pragma unroll
    for (int i = 0; i < CLEN; ++i) P *= df[i];

    __shared__ float sS[NCH][NCOL];
    __shared__ float sP[NCH];
    sS[k][col] = S;
    if (col == 0) sP[k] = P;
    __syncthreads();

    float Cin = 0.f;
    for (int j = 0; j < k; ++j)
        Cin = fmaf(sP[j], Cin, sS[j][col]);

    float* op = out + ((size_t)(b * T_SZ + t0) * D_SZ + r) * D_SZ + c;
    float rp = 1.f;
#pragma unroll
    for (int i = 0; i < CLEN; ++i) {
        rp *= df[i];
        op[(size_t)i * ELEMS] = fmaf(rp, Cin, v[i]);
    }
}

extern "C" void kernel_launch(void* const* d_in, const int* in_sizes, int n_in,
                              void* d_out, int out_size, void* d_ws, size_t ws_size,
                              hipStream_t stream) {
    const float* x     = (const float*)d_in[0];
    const float* log_A = (const float*)d_in[1];
    const float* dt_w  = (const float*)d_in[2];
    const float* dt_b  = (const float*)d_in[3];
    const float* ln_w  = (const float*)d_in[4];
    const float* ln_b  = (const float*)d_in[5];
    float* out     = (float*)d_out;
    float* decay_t = (float*)d_ws;
    float* Mst     = (float*)((char*)d_ws + M_OFF);
    float* Rst     = (float*)((char*)d_ws + R_OFF);

    void* args[] = {
        (void*)&x, (void*)&log_A, (void*)&dt_w, (void*)&dt_b,
        (void*)&ln_w, (void*)&ln_b,
        (void*)&decay_t, (void*)&Mst, (void*)&Rst, (void*)&out
    };
    hipError_t err = hipLaunchCooperativeKernel(
        (const void*)fused_ssm_kernel, dim3(256), dim3(512), args, 0, stream);

    if (err != hipSuccess) {
        // fallback: proven two-kernel path
        ln_dt_kernel<<<B_SZ * T_SZ, 256, 0, stream>>>(
            x, log_A, dt_w, dt_b, ln_w, ln_b, decay_t, Mst, Rst);
        scan_fused_kernel<<<B_SZ * D_SZ * 4, 512, 0, stream>>>(
            x, Mst, Rst, decay_t, ln_w, ln_b, out);
    }
}

// Round 9
// 34.418 us; speedup vs baseline: 1.6445x; 1.6445x over previous
//
#include <hip/hip_runtime.h>
#include <math.h>

#define B_SZ 2
#define T_SZ 512
#define D_SZ 64
#define ELEMS 4096            // D*D
#define CL   16               // timesteps per chunk
#define NK   32               // chunks (NK*CL == T_SZ)
#define NPW  8                // rc-windows per slice
#define WIN  512              // elems per window (NPW*WIN == ELEMS)

// ws layout (bytes)
#define DECAY_OFF   0
#define DECAY_BYTES ((size_t)B_SZ * T_SZ * D_SZ * 4)            // 256 KB  [b][t][r]
#define M_OFF       (DECAY_OFF + DECAY_BYTES)
#define MRB         ((size_t)B_SZ * T_SZ * 4)                    // 4 KB
#define R_OFF       (M_OFF + MRB)
#define PK_OFF      (R_OFF + MRB)
#define PK_BYTES    ((size_t)B_SZ * NK * D_SZ * 4)               // 16 KB  [b][k][r]
#define TAILS_OFF   (PK_OFF + PK_BYTES)
#define TAILS_BYTES ((size_t)B_SZ * NK * ELEMS * 4)              // 1 MB   [b][k][rc]
#define WS_NEEDED   (TAILS_OFF + TAILS_BYTES)

// ---------------- K1: stats + decay + chunk tails (one contiguous x pass) ----
// grid = B*NK = 64 blocks x 1024 threads. Wave wv owns slice t0+wv (lane=row):
// stats via shfl allreduce, row-dot via precomputed wdt table (lane-local).
// Phase 2: thread owns 4 cols of one row, local scan over CL t's (L2-hot
// re-read), writes chunk tail + per-chunk decay product Pk.
__global__ __launch_bounds__(1024, 1) void k1_stats_tails(
    const float* __restrict__ x, const float* __restrict__ log_A,
    const float* __restrict__ dt_w, const float* __restrict__ dt_b,
    const float* __restrict__ ln_w, const float* __restrict__ ln_b,
    float* __restrict__ decay, float* __restrict__ Mst, float* __restrict__ Rst,
    float* __restrict__ Pk, float* __restrict__ tails)
{
    const int tid  = threadIdx.x;
    const int lane = tid & 63;
    const int wv   = tid >> 6;            // 0..15
    const int k    = blockIdx.x & (NK - 1);
    const int b    = blockIdx.x >> 5;
    const int t0   = k * CL;

    __shared__ float s_wdt[D_SZ][D_SZ + 1];   // ln_w * dt_w (padded rows)
    __shared__ float s_W1[D_SZ], s_W0[D_SZ];  // row sums of wdt / ln_b*dt_w
    __shared__ float s_d[CL][D_SZ];           // decay per (slice, row)
    __shared__ float s_m[CL], s_r[CL];        // M = mu*rs, R = rs

    // setup: wdt table + per-row dot constants
    {
        const int r4 = tid >> 4;
        const int c4 = (tid & 15) * 4;
        const float4 lw = *reinterpret_cast<const float4*>(ln_w + r4 * D_SZ + c4);
        const float4 lb = *reinterpret_cast<const float4*>(ln_b + r4 * D_SZ + c4);
        const float4 dw = *reinterpret_cast<const float4*>(dt_w + c4);
        s_wdt[r4][c4 + 0] = lw.x * dw.x;
        s_wdt[r4][c4 + 1] = lw.y * dw.y;
        s_wdt[r4][c4 + 2] = lw.z * dw.z;
        s_wdt[r4][c4 + 3] = lw.w * dw.w;
        float w1 = lw.x * dw.x + lw.y * dw.y + lw.z * dw.z + lw.w * dw.w;
        float w0 = lb.x * dw.x + lb.y * dw.y + lb.z * dw.z + lb.w * dw.w;
#pragma unroll
        for (int m = 1; m <= 8; m <<= 1) {
            w1 += __shfl_xor(w1, m);
            w0 += __shfl_xor(w0, m);
        }
        if ((tid & 15) == 0) { s_W1[r4] = w1; s_W0[r4] = w0; }
    }
    __syncthreads();

    // phase 1: per-wave slice, lane = row
    {
        const int t = t0 + wv;
        const float* xr = x + (size_t)(b * T_SZ + t) * ELEMS + lane * D_SZ;
        float4 xv[16];
#pragma unroll
        for (int q = 0; q < 16; ++q)
            xv[q] = *reinterpret_cast<const float4*>(xr + q * 4);

        float sum = 0.f, ssq = 0.f, sx = 0.f;
        const float* wrow = &s_wdt[lane][0];
#pragma unroll
        for (int q = 0; q < 16; ++q) {
            sum += xv[q].x + xv[q].y + xv[q].z + xv[q].w;
            ssq += xv[q].x * xv[q].x + xv[q].y * xv[q].y
                 + xv[q].z * xv[q].z + xv[q].w * xv[q].w;
            sx  += xv[q].x * wrow[q * 4 + 0] + xv[q].y * wrow[q * 4 + 1]
                 + xv[q].z * wrow[q * 4 + 2] + xv[q].w * wrow[q * 4 + 3];
        }
#pragma unroll
        for (int m = 1; m < 64; m <<= 1) {
            sum += __shfl_xor(sum, m);
            ssq += __shfl_xor(ssq, m);
        }
        const float mu = sum * (1.f / ELEMS);
        const float var = ssq * (1.f / ELEMS) - mu * mu;
        const float rs = rsqrtf(var + 1e-5f);

        const float dot = rs * sx - mu * rs * s_W1[lane] + s_W0[lane];
        const float z = dot + dt_b[0];
        const float dtv = (z > 20.f) ? z : log1pf(expf(z));
        const float Arow = -expf(log_A[lane]);
        const float d = expf(dtv * Arow);

        decay[(size_t)(b * T_SZ + t) * D_SZ + lane] = d;
        s_d[wv][lane] = d;
        if (lane == 0) {
            const float M = mu * rs;
            s_m[wv] = M; s_r[wv] = rs;
            Mst[b * T_SZ + t] = M;
            Rst[b * T_SZ + t] = rs;
        }
    }
    __syncthreads();

    // phase 2: thread owns 4 cols of row tid>>4; local scan over chunk
    {
        const int e = tid * 4;
        const int r = tid >> 4;
        const float4 lw = *reinterpret_cast<const float4*>(ln_w + e);
        const float4 lb = *reinterpret_cast<const float4*>(ln_b + e);
        const float* xp = x + (size_t)(b * T_SZ + t0) * ELEMS + e;

        float4 S = make_float4(0.f, 0.f, 0.f, 0.f);
        float Prow = 1.f;
#pragma unroll
        for (int i = 0; i < CL; ++i) {
            const float4 xv = *reinterpret_cast<const float4*>(xp + (size_t)i * ELEMS);
            const float M = s_m[i], R = s_r[i], d = s_d[i][r];
            const float xn0 = fmaf(fmaf(xv.x, R, -M), lw.x, lb.x);
            const float xn1 = fmaf(fmaf(xv.y, R, -M), lw.y, lb.y);
            const float xn2 = fmaf(fmaf(xv.z, R, -M), lw.z, lb.z);
            const float xn3 = fmaf(fmaf(xv.w, R, -M), lw.w, lb.w);
            S.x = fmaf(S.x, d, xn0);
            S.y = fmaf(S.y, d, xn1);
            S.z = fmaf(S.z, d, xn2);
            S.w = fmaf(S.w, d, xn3);
            Prow *= d;
        }
        *reinterpret_cast<float4*>(tails + ((size_t)(b * NK + k)) * ELEMS + e) = S;
        if ((tid & 15) == 0) Pk[((size_t)(b * NK + k)) * D_SZ + r] = Prow;
    }
}

// ---------------- K2: local fold + apply (one contiguous x pass) -----------
// grid = B*NK*NPW = 512 blocks x 256 threads. Block (b,k,p): fold carry-in
// from tails/Pk (L2-hot), then stream x chunk (L3-hot) -> out contiguously.
__global__ __launch_bounds__(256) void k2_apply(
    const float* __restrict__ x,
    const float* __restrict__ Mst, const float* __restrict__ Rst,
    const float* __restrict__ decay, const float* __restrict__ Pk,
    const float* __restrict__ tails,
    const float* __restrict__ ln_w, const float* __restrict__ ln_b,
    float* __restrict__ out)
{
    const int tid = threadIdx.x;
    const int p = blockIdx.x & (NPW - 1);
    const int k = (blockIdx.x >> 3) & (NK - 1);
    const int b = blockIdx.x >> 8;
    const int rc = p * WIN + tid * 2;
    const int r  = rc >> 6;               // global row
    const int lr = tid >> 5;              // local row 0..7
    const int t0 = k * CL;

    __shared__ float sd[CL][8];
    __shared__ float sm[CL], sr[CL];

    if (tid < CL * 8)
        sd[tid >> 3][tid & 7] =
            decay[(size_t)(b * T_SZ + t0 + (tid >> 3)) * D_SZ + p * 8 + (tid & 7)];
    if (tid < CL) {
        sm[tid] = Mst[b * T_SZ + t0 + tid];
        sr[tid] = Rst[b * T_SZ + t0 + tid];
    }

    const float2 w2 = *reinterpret_cast<const float2*>(ln_w + rc);
    const float2 b2 = *reinterpret_cast<const float2*>(ln_b + rc);

    // carry-in fold: C = tails_j + P_j * C over j < k
    float2 C = make_float2(0.f, 0.f);
    for (int j = 0; j < k; ++j) {
        const float P = Pk[((size_t)(b * NK + j)) * D_SZ + r];
        const float2 tl = *reinterpret_cast<const float2*>(
            tails + ((size_t)(b * NK + j)) * ELEMS + rc);
        C.x = fmaf(P, C.x, tl.x);
        C.y = fmaf(P, C.y, tl.y);
    }
    __syncthreads();

    const float* xp = x + (size_t)(b * T_SZ + t0) * ELEMS + rc;
    float* op = out + (size_t)(b * T_SZ + t0) * ELEMS + rc;
    float2 S = make_float2(0.f, 0.f);
    float cp = 1.f;
#pragma unroll
    for (int i = 0; i < CL; ++i) {
        const float2 xv = *reinterpret_cast<const float2*>(xp + (size_t)i * ELEMS);
        const float M = sm[i], R = sr[i], d = sd[i][lr];
        const float xnx = fmaf(fmaf(xv.x, R, -M), w2.x, b2.x);
        const float xny = fmaf(fmaf(xv.y, R, -M), w2.y, b2.y);
        S.x = fmaf(S.x, d, xnx);
        S.y = fmaf(S.y, d, xny);
        cp *= d;
        float2 o;
        o.x = fmaf(cp, C.x, S.x);
        o.y = fmaf(cp, C.y, S.y);
        *reinterpret_cast<float2*>(op + (size_t)i * ELEMS) = o;
    }
}

// ---------------- tiny safety fallback (never expected; ws proven >= 2.3MB) --
__global__ __launch_bounds__(256) void fb_stats(
    const float* __restrict__ x, const float* __restrict__ log_A,
    const float* __restrict__ dt_w, const float* __restrict__ dt_b,
    const float* __restrict__ ln_w, const float* __restrict__ ln_b,
    float* __restrict__ decay, float* __restrict__ Mst, float* __restrict__ Rst)
{
    const int bt = blockIdx.x, tid = threadIdx.x;
    const size_t base = (size_t)bt * ELEMS;
    float4 v[4];
    float sum = 0.f, ssq = 0.f;
    const float4* xv4 = reinterpret_cast<const float4*>(x + base);
#pragma unroll
    for (int q = 0; q < 4; ++q) {
        v[q] = xv4[tid + 256 * q];
        sum += v[q].x + v[q].y + v[q].z + v[q].w;
        ssq += v[q].x*v[q].x + v[q].y*v[q].y + v[q].z*v[q].z + v[q].w*v[q].w;
    }
    __shared__ float red0[4], red1[4];
#pragma unroll
    for (int off = 32; off; off >>= 1) {
        sum += __shfl_down(sum, off);
        ssq += __shfl_down(ssq, off);
    }
    if ((tid & 63) == 0) { red0[tid >> 6] = sum; red1[tid >> 6] = ssq; }
    __syncthreads();
    sum = red0[0] + red0[1] + red0[2] + red0[3];
    ssq = red1[0] + red1[1] + red1[2] + red1[3];
    const float mu = sum * (1.f / ELEMS);
    const float rs = rsqrtf(ssq * (1.f / ELEMS) - mu * mu + 1e-5f);
    const float4* w4p = reinterpret_cast<const float4*>(ln_w);
    const float4* b4p = reinterpret_cast<const float4*>(ln_b);
    const float4* dw4 = reinterpret_cast<const float4*>(dt_w);
    float dot[4] = {0.f, 0.f, 0.f, 0.f};
#pragma unroll
    for (int q = 0; q < 4; ++q) {
        const int f = tid + 256 * q;
        float4 w4 = w4p[f], b4 = b4p[f], wv = dw4[f & 15];
        dot[q] += (fmaf((v[q].x - mu) * rs, w4.x, b4.x)) * wv.x
                + (fmaf((v[q].y - mu) * rs, w4.y, b4.y)) * wv.y
                + (fmaf((v[q].z - mu) * rs, w4.z, b4.z)) * wv.z
                + (fmaf((v[q].w - mu) * rs, w4.w, b4.w)) * wv.w;
    }
#pragma unroll
    for (int m = 1; m <= 8; m <<= 1)
#pragma unroll
        for (int q = 0; q < 4; ++q) dot[q] += __shfl_xor(dot[q], m);
    if (tid == 0) { Mst[bt] = mu * rs; Rst[bt] = rs; }
    if ((tid & 15) == 0) {
        const float db = dt_b[0];
#pragma unroll
        for (int q = 0; q < 4; ++q) {
            const int r = (tid >> 4) + 16 * q;
            const float z = dot[q] + db;
            const float dtv = (z > 20.f) ? z : log1pf(expf(z));
            decay[(size_t)bt * D_SZ + r] = expf(dtv * -expf(log_A[r]));
        }
    }
}

__global__ __launch_bounds__(256) void fb_scan(
    const float* __restrict__ x,
    const float* __restrict__ Mst, const float* __restrict__ Rst,
    const float* __restrict__ decay,
    const float* __restrict__ ln_w, const float* __restrict__ ln_b,
    float* __restrict__ out)
{
    const int gtid = blockIdx.x * blockDim.x + threadIdx.x;
    const int wid = gtid >> 6, lane = threadIdx.x & 63;
    const int b = wid >> 6, r = wid & 63;
    const float wl = ln_w[r * D_SZ + lane], bl = ln_b[r * D_SZ + lane];
    float S = 0.f;
    for (int t = 0; t < T_SZ; ++t) {
        const size_t off = ((size_t)(b * T_SZ + t) * D_SZ + r) * D_SZ + lane;
        const float M = Mst[b * T_SZ + t], R = Rst[b * T_SZ + t];
        const float d = decay[(size_t)(b * T_SZ + t) * D_SZ + r];
        const float xn = fmaf(fmaf(x[off], R, -M), wl, bl);
        S = fmaf(S, d, xn);
        out[off] = S;
    }
}

extern "C" void kernel_launch(void* const* d_in, const int* in_sizes, int n_in,
                              void* d_out, int out_size, void* d_ws, size_t ws_size,
                              hipStream_t stream) {
    const float* x     = (const float*)d_in[0];
    const float* log_A = (const float*)d_in[1];
    const float* dt_w  = (const float*)d_in[2];
    const float* dt_b  = (const float*)d_in[3];
    const float* ln_w  = (const float*)d_in[4];
    const float* ln_b  = (const float*)d_in[5];
    float* out   = (float*)d_out;
    float* decay = (float*)((char*)d_ws + DECAY_OFF);
    float* Mst   = (float*)((char*)d_ws + M_OFF);
    float* Rst   = (float*)((char*)d_ws + R_OFF);

    if (ws_size >= WS_NEEDED) {
        float* Pkb   = (float*)((char*)d_ws + PK_OFF);
        float* tails = (float*)((char*)d_ws + TAILS_OFF);
        k1_stats_tails<<<B_SZ * NK, 1024, 0, stream>>>(
            x, log_A, dt_w, dt_b, ln_w, ln_b, decay, Mst, Rst, Pkb, tails);
        k2_apply<<<B_SZ * NK * NPW, 256, 0, stream>>>(
            x, Mst, Rst, decay, Pkb, tails, ln_w, ln_b, out);
    } else {
        fb_stats<<<B_SZ * T_SZ, 256, 0, stream>>>(
            x, log_A, dt_w, dt_b, ln_w, ln_b, decay, Mst, Rst);
        fb_scan<<<(B_SZ * D_SZ * 64) / 256, 256, 0, stream>>>(
            x, Mst, Rst, decay, ln_w, ln_b, out);
    }
}

// Round 10
// 23.412 us; speedup vs baseline: 2.4175x; 1.4701x over previous
//
#include <hip/hip_runtime.h>
#include <math.h>

#define B_SZ 2
#define T_SZ 512
#define D_SZ 64
#define ELEMS 4096            // D*D

// K2 geometry: 128 blocks = (b, r). 1024 threads = 64 chunks x 16 col-groups.
// Each thread owns float4 (4 cols) of one row; CLEN = 8 timesteps per chunk.
#define NCH2 64
#define CLEN2 8               // NCH2*CLEN2 == T_SZ
#define NCG  16               // col-groups (16 x float4 = 64 cols)

// ws layout: decay_t [B][D][T] at 0 (256 KB); M=mu*rs [B*T]; R=rs [B*T]
#define DECAY_BYTES ((size_t)B_SZ * D_SZ * T_SZ * 4)
#define M_OFF   DECAY_BYTES
#define R_OFF   (DECAY_BYTES + (size_t)B_SZ * T_SZ * 4)

// Kernel 1 (unchanged, proven): per-(b,t) LN stats + row-dot + decay.
__global__ __launch_bounds__(256) void ln_dt_kernel(
    const float* __restrict__ x, const float* __restrict__ log_A,
    const float* __restrict__ dt_w, const float* __restrict__ dt_b,
    const float* __restrict__ ln_w, const float* __restrict__ ln_b,
    float* __restrict__ decay_t, float* __restrict__ Mst, float* __restrict__ Rst)
{
    const int bt  = blockIdx.x;
    const int tid = threadIdx.x;
    const size_t base = (size_t)bt * ELEMS;

    float4 v[4];
    float sum = 0.f, sumsq = 0.f;
    const float4* xv4 = reinterpret_cast<const float4*>(x + base);
#pragma unroll
    for (int k = 0; k < 4; ++k) {
        v[k] = xv4[tid + 256 * k];
        sum   += v[k].x + v[k].y + v[k].z + v[k].w;
        sumsq += v[k].x * v[k].x + v[k].y * v[k].y + v[k].z * v[k].z + v[k].w * v[k].w;
    }

    __shared__ float red0[4], red1[4];
#pragma unroll
    for (int off = 32; off; off >>= 1) {
        sum   += __shfl_down(sum, off);
        sumsq += __shfl_down(sumsq, off);
    }
    const int wave = tid >> 6;
    if ((tid & 63) == 0) { red0[wave] = sum; red1[wave] = sumsq; }
    __syncthreads();
    sum   = red0[0] + red0[1] + red0[2] + red0[3];
    sumsq = red1[0] + red1[1] + red1[2] + red1[3];

    const float mu = sum * (1.f / ELEMS);
    const float var = sumsq * (1.f / ELEMS) - mu * mu;
    const float rs = rsqrtf(var + 1e-5f);

    const float4* w4p = reinterpret_cast<const float4*>(ln_w);
    const float4* b4p = reinterpret_cast<const float4*>(ln_b);
    const float4* dw4 = reinterpret_cast<const float4*>(dt_w);
    float dot[4] = {0.f, 0.f, 0.f, 0.f};
#pragma unroll
    for (int k = 0; k < 4; ++k) {
        const int f = tid + 256 * k;
        float4 w4 = w4p[f];
        float4 b4 = b4p[f];
        float4 xn;
        xn.x = (v[k].x - mu) * rs * w4.x + b4.x;
        xn.y = (v[k].y - mu) * rs * w4.y + b4.y;
        xn.z = (v[k].z - mu) * rs * w4.z + b4.z;
        xn.w = (v[k].w - mu) * rs * w4.w + b4.w;
        float4 wv = dw4[f & 15];
        dot[k] += xn.x * wv.x + xn.y * wv.y + xn.z * wv.z + xn.w * wv.w;
    }

#pragma unroll
    for (int m = 1; m <= 8; m <<= 1) {
#pragma unroll
        for (int k = 0; k < 4; ++k) dot[k] += __shfl_xor(dot[k], m);
    }

    if (tid == 0) { Mst[bt] = mu * rs; Rst[bt] = rs; }

    if ((tid & 15) == 0) {
        const int m = tid >> 4;
        const float db = dt_b[0];
        const int b = bt >> 9;
        const int t = bt & (T_SZ - 1);
#pragma unroll
        for (int k = 0; k < 4; ++k) {
            const int r = m + 16 * k;
            const float z = dot[k] + db;
            const float dt = (z > 20.f) ? z : log1pf(expf(z));
            const float A = -expf(log_A[r]);
            decay_t[((size_t)(b * D_SZ + r)) * T_SZ + t] = expf(dt * A);
        }
    }
}

// Kernel 2: block = (b, r). 1024 threads = 64 chunks x 16 col-groups (float4).
// All global reads/writes are 256B-contiguous row segments. Scalars in LDS
// (broadcast reads). Cross-chunk carry via LDS fold (depth 64).
__global__ __launch_bounds__(1024, 1) void scan_row4_kernel(
    const float* __restrict__ x,
    const float* __restrict__ Mst, const float* __restrict__ Rst,
    const float* __restrict__ decay_t,
    const float* __restrict__ ln_w, const float* __restrict__ ln_b,
    float* __restrict__ out)
{
    const int tid = threadIdx.x;
    const int cg  = tid & (NCG - 1);      // col-group 0..15
    const int k   = tid >> 4;             // chunk 0..63
    const int b   = blockIdx.x >> 6;
    const int r   = blockIdx.x & 63;
    const int t0  = k * CLEN2;
    const int c0  = cg * 4;

    __shared__ float  sd[T_SZ];
    __shared__ float  sM[T_SZ];
    __shared__ float  sR[T_SZ];
    __shared__ float4 sS[NCH2][NCG];
    __shared__ float  sP[NCH2];

    // stage scalars (vectorized, disjoint thread ranges)
    if (tid < 128) {
        reinterpret_cast<float4*>(sd)[tid] =
            reinterpret_cast<const float4*>(decay_t + (size_t)blockIdx.x * T_SZ)[tid];
    } else if (tid < 256) {
        const int i = tid - 128;
        reinterpret_cast<float4*>(sM)[i] =
            reinterpret_cast<const float4*>(Mst + b * T_SZ)[i];
    } else if (tid < 384) {
        const int i = tid - 256;
        reinterpret_cast<float4*>(sR)[i] =
            reinterpret_cast<const float4*>(Rst + b * T_SZ)[i];
    }
    const float4 lw = *reinterpret_cast<const float4*>(ln_w + r * D_SZ + c0);
    const float4 lb = *reinterpret_cast<const float4*>(ln_b + r * D_SZ + c0);
    __syncthreads();

    const float* xp = x + ((size_t)(b * T_SZ + t0) * D_SZ + r) * D_SZ + c0;

    // local inclusive scan, float4 per thread, chain length 8
    float4 v[CLEN2];
    float4 S = make_float4(0.f, 0.f, 0.f, 0.f);
    float  P = 1.f;
#pragma unroll
    for (int i = 0; i < CLEN2; ++i) {
        const float4 xv = *reinterpret_cast<const float4*>(xp + (size_t)i * ELEMS);
        const int   t = t0 + i;
        const float M = sM[t], R = sR[t], d = sd[t];
        const float xn0 = fmaf(fmaf(xv.x, R, -M), lw.x, lb.x);
        const float xn1 = fmaf(fmaf(xv.y, R, -M), lw.y, lb.y);
        const float xn2 = fmaf(fmaf(xv.z, R, -M), lw.z, lb.z);
        const float xn3 = fmaf(fmaf(xv.w, R, -M), lw.w, lb.w);
        S.x = fmaf(S.x, d, xn0);
        S.y = fmaf(S.y, d, xn1);
        S.z = fmaf(S.z, d, xn2);
        S.w = fmaf(S.w, d, xn3);
        P *= d;
        v[i] = S;
    }

    sS[k][cg] = S;
    if (cg == 0) sP[k] = P;
    __syncthreads();

    // carry-in fold over chunks j < k (LDS broadcasts, depth <= 63)
    float4 C = make_float4(0.f, 0.f, 0.f, 0.f);
    for (int j = 0; j < k; ++j) {
        const float  Pj = sP[j];
        const float4 Sj = sS[j][cg];
        C.x = fmaf(Pj, C.x, Sj.x);
        C.y = fmaf(Pj, C.y, Sj.y);
        C.z = fmaf(Pj, C.z, Sj.z);
        C.w = fmaf(Pj, C.w, Sj.w);
    }

    // apply carry and write (256B-contiguous stores)
    float* op = out + ((size_t)(b * T_SZ + t0) * D_SZ + r) * D_SZ + c0;
    float rp = 1.f;
#pragma unroll
    for (int i = 0; i < CLEN2; ++i) {
        rp *= sd[t0 + i];
        float4 o;
        o.x = fmaf(rp, C.x, v[i].x);
        o.y = fmaf(rp, C.y, v[i].y);
        o.z = fmaf(rp, C.z, v[i].z);
        o.w = fmaf(rp, C.w, v[i].w);
        *reinterpret_cast<float4*>(op + (size_t)i * ELEMS) = o;
    }
}

extern "C" void kernel_launch(void* const* d_in, const int* in_sizes, int n_in,
                              void* d_out, int out_size, void* d_ws, size_t ws_size,
                              hipStream_t stream) {
    const float* x     = (const float*)d_in[0];
    const float* log_A = (const float*)d_in[1];
    const float* dt_w  = (const float*)d_in[2];
    const float* dt_b  = (const float*)d_in[3];
    const float* ln_w  = (const float*)d_in[4];
    const float* ln_b  = (const float*)d_in[5];
    float* out     = (float*)d_out;
    float* decay_t = (float*)d_ws;
    float* Mst     = (float*)((char*)d_ws + M_OFF);
    float* Rst     = (float*)((char*)d_ws + R_OFF);

    ln_dt_kernel<<<B_SZ * T_SZ, 256, 0, stream>>>(
        x, log_A, dt_w, dt_b, ln_w, ln_b, decay_t, Mst, Rst);

    scan_row4_kernel<<<B_SZ * D_SZ, 1024, 0, stream>>>(
        x, Mst, Rst, decay_t, ln_w, ln_b, out);
}